// Round 12
// baseline (195.102 us; speedup 1.0000x reference)
//
#include <hip/hip_runtime.h>
#include <math.h>

#define Q_LEN 512
#define M_LEN 512
#define KL    1024
#define BSZ   4
#define DM    1024
#define NH    16
#define DHD   64
#define NG    4
#define DGRP  256
#define RL    1024
#define LN_EPS 1e-6f
#define ATT_SCALE 0.125f

typedef short s16x8 __attribute__((ext_vector_type(8)));
typedef float f32x4 __attribute__((ext_vector_type(4)));

__device__ __forceinline__ float wave_sum64(float v) {
#pragma unroll
    for (int off = 32; off > 0; off >>= 1) v += __shfl_xor(v, off);
    return v;
}

__device__ __forceinline__ ushort f2bf(float f) {
    unsigned u = __float_as_uint(f);
    unsigned r = (u + 0x7fffu + ((u >> 16) & 1u)) >> 16;   // RNE
    return (ushort)r;
}
__device__ __forceinline__ float bf2f(ushort u) {
    return __uint_as_float(((unsigned)u) << 16);
}

// ---------------- f32 -> bf16 cast of r, Wk, Wv, Wr ----------------
__global__ __launch_bounds__(256) void cast4_kernel(
    const float* p0, const float* p1, const float* p2, const float* p3,
    ushort* d0, ushort* d1, ushort* d2, ushort* d3)
{
    int bid = blockIdx.x;
    const float* s; ushort* d; int off;
    if      (bid < 1024) { s = p0; d = d0; off = bid; }
    else if (bid < 2048) { s = p1; d = d1; off = bid - 1024; }
    else if (bid < 3072) { s = p2; d = d2; off = bid - 2048; }
    else                 { s = p3; d = d3; off = bid - 3072; }
    int i = off * 1024 + threadIdx.x * 4;
    float4 v = *(const float4*)(s + i);
    ushort4 o;
    o.x = f2bf(v.x); o.y = f2bf(v.y); o.z = f2bf(v.z); o.w = f2bf(v.w);
    *(ushort4*)(d + i) = o;
}

// ---- augmented weights: W'[g][o][k] = Wfull[o][k] + (k>>8==g ? Wg[g][o][k&255] : 0)
__global__ __launch_bounds__(256) void augment_kernel(
    const float* __restrict__ Wg0, const float* __restrict__ Wf0, ushort* __restrict__ Wo0,
    const float* __restrict__ Wg1, const float* __restrict__ Wf1, ushort* __restrict__ Wo1)
{
    int bid = blockIdx.x;
    const float* Wg; const float* Wf; ushort* Wo; int off;
    if (bid < 1024) { Wg = Wg0; Wf = Wf0; Wo = Wo0; off = bid; }
    else            { Wg = Wg1; Wf = Wf1; Wo = Wo1; off = bid - 1024; }
    int idx = off * 1024 + threadIdx.x * 4;      // over 4*256*1024
    int g = idx >> 18;
    int o = (idx >> 10) & 255;
    int k = idx & 1023;
    float4 v = *(const float4*)(Wf + o * 1024 + k);
    if ((k >> 8) == g) {
        float4 vg = *(const float4*)(Wg + ((g * 256 + o) << 8) + (k & 255));
        v.x += vg.x; v.y += vg.y; v.z += vg.z; v.w += vg.w;
    }
    ushort4 u;
    u.x = f2bf(v.x); u.y = f2bf(v.y); u.z = f2bf(v.z); u.w = f2bf(v.w);
    *(ushort4*)(Wo + idx) = u;
}

// ---------------- group LayerNorm for w (G=4 groups of 256) -> bf16 --------
__global__ __launch_bounds__(64) void group_ln_kernel(
    const float* __restrict__ w, const float* __restrict__ gamma,
    const float* __restrict__ beta, ushort* __restrict__ out)
{
    int bid = blockIdx.x;              // (q*BSZ + b)*NG + g
    int g = bid & (NG - 1);
    long long row = bid >> 2;
    int t = threadIdx.x;
    long long base = row * DM + g * DGRP + t * 4;
    float4 x = *(const float4*)(w + base);
    float mean = wave_sum64(x.x + x.y + x.z + x.w) * (1.0f / 256.0f);
    float dx = x.x - mean, dy = x.y - mean, dz = x.z - mean, dw = x.w - mean;
    float ss = wave_sum64(dx * dx + dy * dy + dz * dz + dw * dw);
    float inv = 1.0f / (sqrtf(ss * (1.0f / 255.0f)) + LN_EPS);   // ddof=1
    int db = g * DGRP + t * 4;
    float4 ga = *(const float4*)(gamma + db);
    float4 be = *(const float4*)(beta + db);
    ushort4 o;
    o.x = f2bf(ga.x * (dx * inv) + be.x);
    o.y = f2bf(ga.y * (dy * inv) + be.y);
    o.z = f2bf(ga.z * (dz * inv) + be.z);
    o.w = f2bf(ga.w * (dw * inv) + be.w);
    *(ushort4*)(out + base) = o;
}

// ---------------- full LayerNorm for kv = concat(mems, w) -> bf16 ----------
__global__ __launch_bounds__(256) void kv_ln_kernel(
    const float* __restrict__ mems, const float* __restrict__ w,
    const float* __restrict__ gamma, const float* __restrict__ beta,
    ushort* __restrict__ out)
{
    int row = blockIdx.x;              // k*BSZ + b
    int k = row >> 2, b = row & 3;
    const float* src = (k < M_LEN) ? (mems + ((long long)k * BSZ + b) * DM)
                                   : (w + ((long long)(k - M_LEN) * BSZ + b) * DM);
    int t = threadIdx.x;
    float4 x = *(const float4*)(src + t * 4);
    __shared__ float red[4];
    float s = wave_sum64(x.x + x.y + x.z + x.w);
    int wv = t >> 6, ln = t & 63;
    if (ln == 0) red[wv] = s;
    __syncthreads();
    float mean = (red[0] + red[1] + red[2] + red[3]) * (1.0f / 1024.0f);
    float dx = x.x - mean, dy = x.y - mean, dz = x.z - mean, dw = x.w - mean;
    float ss = wave_sum64(dx * dx + dy * dy + dz * dz + dw * dw);
    __syncthreads();
    if (ln == 0) red[wv] = ss;
    __syncthreads();
    float var = (red[0] + red[1] + red[2] + red[3]) * (1.0f / 1023.0f);
    float inv = 1.0f / (sqrtf(var) + LN_EPS);
    int db = t * 4;
    float4 ga = *(const float4*)(gamma + db);
    float4 be = *(const float4*)(beta + db);
    ushort4 o;
    o.x = f2bf(ga.x * (dx * inv) + be.x);
    o.y = f2bf(ga.y * (dy * inv) + be.y);
    o.z = f2bf(ga.z * (dz * inv) + be.z);
    o.w = f2bf(ga.w * (dw * inv) + be.w);
    *(ushort4*)(out + (long long)row * DM + db) = o;
}

// ------ 128x128-tile bf16 MFMA GEMM  Cb = A[M,K] * W[N,K]^T (bf16 out) -----
__global__ __launch_bounds__(256) void gemm128_bf16_nt(
    const ushort* __restrict__ A, int lda,
    const ushort* __restrict__ W, long long wZ, int ldw,
    ushort* __restrict__ Cb, long long cZ, int ldc, int K)
{
    int z = blockIdx.z;
    W += (long long)z * wZ;
    Cb += (long long)z * cZ;
    int m0 = blockIdx.y * 128, n0 = blockIdx.x * 128;
    int t = threadIdx.x, lane = t & 63, w = t >> 6;
    int wr = w >> 1, wc = w & 1;
    int fr = lane & 15, kq = (lane >> 4) * 8;
    int srow = t >> 1, scol = (t & 1) * 16;

    __shared__ __align__(16) ushort As[128][40];
    __shared__ __align__(16) ushort Ws[128][40];

    const ushort* Ar = A + (long long)(m0 + srow) * lda + scol;
    const ushort* Wr = W + (long long)(n0 + srow) * ldw + scol;

    f32x4 acc[16] = {};

    s16x8 a0 = *(const s16x8*)Ar, a1 = *(const s16x8*)(Ar + 8);
    s16x8 b0 = *(const s16x8*)Wr, b1 = *(const s16x8*)(Wr + 8);
    *(s16x8*)&As[srow][scol] = a0; *(s16x8*)&As[srow][scol + 8] = a1;
    *(s16x8*)&Ws[srow][scol] = b0; *(s16x8*)&Ws[srow][scol + 8] = b1;
    __syncthreads();

    for (int k0 = 0; k0 < K; k0 += 32) {
        bool more = (k0 + 32) < K;
        if (more) {
            a0 = *(const s16x8*)(Ar + k0 + 32); a1 = *(const s16x8*)(Ar + k0 + 40);
            b0 = *(const s16x8*)(Wr + k0 + 32); b1 = *(const s16x8*)(Wr + k0 + 40);
        }
        s16x8 af[4], bf_[4];
#pragma unroll
        for (int rb = 0; rb < 4; ++rb)
            af[rb] = *(const s16x8*)&As[wr * 64 + rb * 16 + fr][kq];
#pragma unroll
        for (int cb = 0; cb < 4; ++cb)
            bf_[cb] = *(const s16x8*)&Ws[wc * 64 + cb * 16 + fr][kq];
#pragma unroll
        for (int rb = 0; rb < 4; ++rb)
#pragma unroll
            for (int cb = 0; cb < 4; ++cb)
                acc[rb * 4 + cb] = __builtin_amdgcn_mfma_f32_16x16x32_bf16(
                    af[rb], bf_[cb], acc[rb * 4 + cb], 0, 0, 0);
        __syncthreads();
        if (more) {
            *(s16x8*)&As[srow][scol] = a0; *(s16x8*)&As[srow][scol + 8] = a1;
            *(s16x8*)&Ws[srow][scol] = b0; *(s16x8*)&Ws[srow][scol + 8] = b1;
            __syncthreads();
        }
    }

    int rbase = (lane >> 4) * 4;
#pragma unroll
    for (int rb = 0; rb < 4; ++rb)
#pragma unroll
        for (int p = 0; p < 4; ++p) {
            long long row = m0 + wr * 64 + rb * 16 + rbase + p;
            ushort* crow = Cb + row * ldc + n0 + wc * 64 + fr;
#pragma unroll
            for (int cb = 0; cb < 4; ++cb)
                crow[cb * 16] = f2bf(acc[rb * 4 + cb][p]);
        }
}

// ------ 64x64-tile bf16 MFMA GEMM (BK=64 + reg prefetch), f32/bf16 out -----
__global__ __launch_bounds__(256) void gemm_bf16_nt(
    const ushort* __restrict__ A, long long aZ, int lda,
    const ushort* __restrict__ W, long long wZ, int ldw,
    float* __restrict__ C, ushort* __restrict__ Cb, long long cZ, int ldc,
    int M, int N, int K,
    const float* __restrict__ add1, long long a1Z, int lda1,
    const float* __restrict__ add2, long long a2Z, int lda2)
{
    int z = blockIdx.z;
    A += (long long)z * aZ;
    W += (long long)z * wZ;
    if (C)  C += (long long)z * cZ;
    if (Cb) Cb += (long long)z * cZ;
    if (add1) add1 += (long long)z * a1Z;
    if (add2) add2 += (long long)z * a2Z;
    int m0 = blockIdx.y * 64, n0 = blockIdx.x * 64;
    int t = threadIdx.x;
    int lane = t & 63, wid = t >> 6;
    int wr = wid >> 1, wc = wid & 1;
    int srow = t >> 2, scol = (t & 3) * 16;
    int fr = lane & 15, kq = (lane >> 4) * 8;

    __shared__ __align__(16) ushort As[64][72];
    __shared__ __align__(16) ushort Ws[64][72];

    f32x4 acc00 = {}, acc01 = {}, acc10 = {}, acc11 = {};

    const ushort* Arow = A + (long long)(m0 + srow) * lda + scol;
    const ushort* Wrow = W + (long long)(n0 + srow) * ldw + scol;

    s16x8 ra0 = *(const s16x8*)Arow;
    s16x8 ra1 = *(const s16x8*)(Arow + 8);
    s16x8 rw0 = *(const s16x8*)Wrow;
    s16x8 rw1 = *(const s16x8*)(Wrow + 8);
    *(s16x8*)&As[srow][scol] = ra0; *(s16x8*)&As[srow][scol + 8] = ra1;
    *(s16x8*)&Ws[srow][scol] = rw0; *(s16x8*)&Ws[srow][scol + 8] = rw1;
    __syncthreads();

    for (int k0 = 0; k0 < K; k0 += 64) {
        bool hasNext = (k0 + 64) < K;
        if (hasNext) {
            ra0 = *(const s16x8*)(Arow + k0 + 64);
            ra1 = *(const s16x8*)(Arow + k0 + 72);
            rw0 = *(const s16x8*)(Wrow + k0 + 64);
            rw1 = *(const s16x8*)(Wrow + k0 + 72);
        }
#pragma unroll
        for (int kk = 0; kk < 64; kk += 32) {
            s16x8 a0 = *(const s16x8*)&As[wr * 32 + fr][kk + kq];
            s16x8 a1 = *(const s16x8*)&As[wr * 32 + 16 + fr][kk + kq];
            s16x8 b0 = *(const s16x8*)&Ws[wc * 32 + fr][kk + kq];
            s16x8 b1 = *(const s16x8*)&Ws[wc * 32 + 16 + fr][kk + kq];
            acc00 = __builtin_amdgcn_mfma_f32_16x16x32_bf16(a0, b0, acc00, 0, 0, 0);
            acc01 = __builtin_amdgcn_mfma_f32_16x16x32_bf16(a0, b1, acc01, 0, 0, 0);
            acc10 = __builtin_amdgcn_mfma_f32_16x16x32_bf16(a1, b0, acc10, 0, 0, 0);
            acc11 = __builtin_amdgcn_mfma_f32_16x16x32_bf16(a1, b1, acc11, 0, 0, 0);
        }
        __syncthreads();
        if (hasNext) {
            *(s16x8*)&As[srow][scol] = ra0; *(s16x8*)&As[srow][scol + 8] = ra1;
            *(s16x8*)&Ws[srow][scol] = rw0; *(s16x8*)&Ws[srow][scol + 8] = rw1;
            __syncthreads();
        }
    }

    int rbase = (lane >> 4) * 4;
#pragma unroll
    for (int p = 0; p < 4; ++p) {
        int mrow0 = wr * 32 + rbase + p;
        int mrow1 = mrow0 + 16;
        int ncol0 = wc * 32 + fr;
        int ncol1 = ncol0 + 16;
        float v00 = acc00[p], v01 = acc01[p], v10 = acc10[p], v11 = acc11[p];
        long long r0 = m0 + mrow0, r1 = m0 + mrow1;
        int c0 = n0 + ncol0, c1 = n0 + ncol1;
        if (add1) {
            v00 += add1[r0 * lda1 + c0]; v01 += add1[r0 * lda1 + c1];
            v10 += add1[r1 * lda1 + c0]; v11 += add1[r1 * lda1 + c1];
        }
        if (add2) {
            v00 += add2[r0 * lda2 + c0]; v01 += add2[r0 * lda2 + c1];
            v10 += add2[r1 * lda2 + c0]; v11 += add2[r1 * lda2 + c1];
        }
        if (Cb) {
            Cb[r0 * ldc + c0] = f2bf(v00); Cb[r0 * ldc + c1] = f2bf(v01);
            Cb[r1 * ldc + c0] = f2bf(v10); Cb[r1 * ldc + c1] = f2bf(v11);
        } else {
            C[r0 * ldc + c0] = v00; C[r0 * ldc + c1] = v01;
            C[r1 * ldc + c0] = v10; C[r1 * ldc + c1] = v11;
        }
    }
}

// --------- transpose head_v: [k*4+b][n*64+d] -> [(b*16+n)*64+d][k] ---------
__global__ __launch_bounds__(256) void transpose_v_kernel(
    const ushort* __restrict__ vin, ushort* __restrict__ vout)
{
    __shared__ __align__(16) ushort T[64][72];
    int bn = blockIdx.y;
    int b = bn >> 4, n = bn & 15;
    int k0 = blockIdx.x * 64;
    int t = threadIdx.x;
    {
        int kr = t >> 2, dp = (t & 3) * 16;
        const ushort* sp = vin + (((long long)(k0 + kr)) * 4 + b) * DM + n * DHD + dp;
        *(s16x8*)&T[kr][dp] = *(const s16x8*)sp;
        *(s16x8*)&T[kr][dp + 8] = *(const s16x8*)(sp + 8);
    }
    __syncthreads();
    {
        int d = t >> 2, kp = (t & 3) * 16;
        ushort vals[16];
#pragma unroll
        for (int q = 0; q < 16; ++q) vals[q] = T[kp + q][d];
        ushort* dp = vout + ((long long)bn * DHD + d) * KL + k0 + kp;
        *(s16x8*)dp = *(const s16x8*)&vals[0];
        *(s16x8*)(dp + 8) = *(const s16x8*)&vals[8];
    }
}

// --------- corr[n,k] = sum_d (rrb[n,d]-rwb[n,d]) * r_head_k[k,n,d] ---------
__global__ __launch_bounds__(256) void corr_kernel(
    const ushort* __restrict__ r_hk, const float* __restrict__ rwb,
    const float* __restrict__ rrb, float* __restrict__ corr)
{
    int n = blockIdx.y;
    int k = blockIdx.x * 4 + (threadIdx.x >> 6);
    int d = threadIdx.x & 63;
    float diff = rrb[n * DHD + d] - rwb[n * DHD + d];
    float v = diff * bf2f(r_hk[(long long)k * DM + n * DHD + d]);
    v = wave_sum64(v);
    if (d == 0) corr[n * RL + k] = v;
}

// ---------------- barrier-free 1-wave rel-shift attention (kv-split 2) -----
// grid (64, 64): x = iw*2+s (iw: 16-row q-wave, s: kv segment); y = b*16+n.
// No staging, no barriers: K/V/RK fragments read directly from global (L2/L3).
// Outputs UNNORMALIZED O (f32) + per-row (m,l) partials; merged by merge_kernel.
__global__ __launch_bounds__(64, 4) void attn_split_kernel(
    const ushort* __restrict__ hq, const ushort* __restrict__ hk,
    const ushort* __restrict__ hvT, const ushort* __restrict__ rhk,
    const float* __restrict__ corr,
    float* __restrict__ Op0, float* __restrict__ Op1, float* __restrict__ Ml)
{
    __shared__ __align__(16) ushort BDs[16][128];   // wave-private ring, XOR-swz
    __shared__ __align__(16) ushort Ps[16][64];     // wave-private, XOR-swz

    int bx = blockIdx.x;
    int iw = bx >> 1, s = bx & 1;
    int bh = blockIdx.y;
    int b = bh >> 4, n = bh & 15;
    int i0 = iw * 16;
    int lane = threadIdx.x;
    int lr16 = lane & 15;
    int hi = lane >> 4;
    int lk8 = hi * 8;
    int orow = hi * 4;
    int swzBD = (hi & 3) << 4;

    // Q frag rows i0 + lr16 (head_q already includes r_w_bias)
    const ushort* qp = hq + (((long long)(i0 + lr16)) * 4 + b) * DM + n * DHD + lk8;
    s16x8 qf0 = *(const s16x8*)qp;
    s16x8 qf1 = *(const s16x8*)(qp + 32);

    f32x4 O[4] = {};
    float m_[4], l_[4];
#pragma unroll
    for (int r = 0; r < 4; ++r) { m_[r] = -INFINITY; l_[r] = 0.0f; }

    int nJ = ((i0 + 527) >> 6) + 1;
    if (nJ > 16) nJ = 16;
    int h = (nJ + 1) >> 1;
    int jts = s ? h : 0, jte = s ? nJ : h;
    int ka0 = 496 - i0;                  // >= 0

    for (int jt = jts; jt < jte; ++jt) {
        int j0 = jt * 64;
        int ka = ka0 + j0;

        // ---- AC (8 MFMA), K frags from global ----
        f32x4 ac[4] = {};
#pragma unroll
        for (int nb = 0; nb < 4; ++nb) {
            const ushort* kp = hk + (((long long)(j0 + nb * 16 + lr16)) * 4 + b) * DM
                                  + n * DHD + lk8;
            s16x8 kb0 = *(const s16x8*)kp;
            s16x8 kb1 = *(const s16x8*)(kp + 32);
            ac[nb] = __builtin_amdgcn_mfma_f32_16x16x32_bf16(qf0, kb0, ac[nb], 0, 0, 0);
            ac[nb] = __builtin_amdgcn_mfma_f32_16x16x32_bf16(qf1, kb1, ac[nb], 0, 0, 0);
        }

        // ---- BD: segment-first tile all 128 cols, later tiles only new 64 ----
        int nb0 = (jt == jts) ? 0 : 4;
        for (int nb = nb0; nb < 8; ++nb) {
            int kk = nb * 16 + lr16;
            int rabs = ka + kk;
            int phys = rabs & 127;
            s16x8 rb0 = {}, rb1 = {};
            float cadd = 0.0f;
            if (rabs < RL) {
                const ushort* rp = rhk + (long long)rabs * DM + n * DHD + lk8;
                rb0 = *(const s16x8*)rp;
                rb1 = *(const s16x8*)(rp + 32);
                cadd = corr[n * RL + rabs];
            }
            f32x4 bd = {};
            bd = __builtin_amdgcn_mfma_f32_16x16x32_bf16(qf0, rb0, bd, 0, 0, 0);
            bd = __builtin_amdgcn_mfma_f32_16x16x32_bf16(qf1, rb1, bd, 0, 0, 0);
            int colw = phys ^ swzBD;
#pragma unroll
            for (int reg = 0; reg < 4; ++reg)
                BDs[orow + reg][colw] = f2bf(bd[reg] + cadd);
        }

        // ---- rel-shift assembly + batched online softmax ----
        float pvv[4][4], rowm[4];
#pragma unroll
        for (int reg = 0; reg < 4; ++reg) {
            int il = orow + reg;
            int i = i0 + il;
            rowm[reg] = -INFINITY;
#pragma unroll
            for (int nb = 0; nb < 4; ++nb) {
                int jc = nb * 16 + lr16;
                int j = j0 + jc;
                float sv = -INFINITY;
                if (j <= i + M_LEN) {
                    int phys = (j + 511 - i) & 127;
                    sv = (ac[nb][reg] + bf2f(BDs[il][phys ^ swzBD])) * ATT_SCALE;
                }
                pvv[reg][nb] = sv;
                rowm[reg] = fmaxf(rowm[reg], sv);
            }
        }
#pragma unroll
        for (int st = 1; st <= 8; st <<= 1)
#pragma unroll
            for (int reg = 0; reg < 4; ++reg)
                rowm[reg] = fmaxf(rowm[reg], __shfl_xor(rowm[reg], st));
        float rs[4], alpha[4];
#pragma unroll
        for (int reg = 0; reg < 4; ++reg) {
            int il = orow + reg;
            float newm = fmaxf(m_[reg], rowm[reg]);
            alpha[reg] = __expf(m_[reg] - newm);
            m_[reg] = newm;
            rs[reg] = 0.0f;
#pragma unroll
            for (int nb = 0; nb < 4; ++nb) {
                float p = __expf(pvv[reg][nb] - newm);
                rs[reg] += p;
                int jc = nb * 16 + lr16;
                int colp = (((jc >> 3) ^ (il & 7)) << 3) | (jc & 7);
                Ps[il][colp] = f2bf(p);
            }
        }
#pragma unroll
        for (int st = 1; st <= 8; st <<= 1)
#pragma unroll
            for (int reg = 0; reg < 4; ++reg)
                rs[reg] += __shfl_xor(rs[reg], st);
#pragma unroll
        for (int reg = 0; reg < 4; ++reg) {
            l_[reg] = l_[reg] * alpha[reg] + rs[reg];
#pragma unroll
            for (int nb = 0; nb < 4; ++nb) O[nb][reg] *= alpha[reg];
        }

        // ---- PV (8 MFMA), V^T frags from global ----
        {
            int rh = lr16 & 7;
#pragma unroll
            for (int kc = 0; kc < 2; ++kc) {
                int blk = kc * 4 + hi;
                s16x8 pa = *(const s16x8*)&Ps[lr16][(blk ^ rh) << 3];
#pragma unroll
                for (int nb = 0; nb < 4; ++nb) {
                    const ushort* vp = hvT + ((long long)(bh * DHD + nb * 16 + lr16)) * KL
                                           + j0 + kc * 32 + lk8;
                    s16x8 vb = *(const s16x8*)vp;
                    O[nb] = __builtin_amdgcn_mfma_f32_16x16x32_bf16(pa, vb, O[nb], 0, 0, 0);
                }
            }
        }
    }

    // ---- epilogue: unnormalized O (f32) + (m,l) ----
    float* Ob = s ? Op1 : Op0;
#pragma unroll
    for (int reg = 0; reg < 4; ++reg) {
        int il = orow + reg;
        long long i = i0 + il;
#pragma unroll
        for (int nb = 0; nb < 4; ++nb)
            Ob[(i * 4 + b) * DM + n * DHD + nb * 16 + lr16] = O[nb][reg];
    }
    if (lr16 == 0) {
#pragma unroll
        for (int reg = 0; reg < 4; ++reg) {
            int i = i0 + orow + reg;
            long long ridx = ((long long)s * 32768 + ((i * 4 + b) * 16 + n)) * 2;
            Ml[ridx] = m_[reg];
            Ml[ridx + 1] = l_[reg];
        }
    }
}

// ---------------- merge the two kv-segment partials -> bf16 attn_o ---------
__global__ __launch_bounds__(256) void merge_kernel(
    const float* __restrict__ Op0, const float* __restrict__ Op1,
    const float* __restrict__ Ml, ushort* __restrict__ outb)
{
    int gid = blockIdx.x * 256 + threadIdx.x;    // 524288
    int row = gid >> 4;
    int d4 = (gid & 15) * 4;
    float m0 = Ml[row * 2], l0 = Ml[row * 2 + 1];
    float m1 = Ml[65536 + row * 2], l1 = Ml[65536 + row * 2 + 1];
    float M = fmaxf(m0, m1);
    float w0 = __expf(m0 - M), w1 = __expf(m1 - M);
    float den = l0 * w0 + l1 * w1;
    float s0 = w0 / den, s1 = w1 / den;
    long long off = (long long)row * 64 + d4;
    float4 o0 = *(const float4*)(Op0 + off);
    float4 o1 = *(const float4*)(Op1 + off);
    ushort4 o;
    o.x = f2bf(o0.x * s0 + o1.x * s1);
    o.y = f2bf(o0.y * s0 + o1.y * s1);
    o.z = f2bf(o0.z * s0 + o1.z * s1);
    o.w = f2bf(o0.w * s0 + o1.w * s1);
    *(ushort4*)(outb + off) = o;
}

extern "C" void kernel_launch(void* const* d_in, const int* in_sizes, int n_in,
                              void* d_out, int out_size, void* d_ws, size_t ws_size,
                              hipStream_t stream) {
    const float* w       = (const float*)d_in[0];
    const float* r       = (const float*)d_in[1];
    const float* rwb     = (const float*)d_in[2];
    const float* rrb     = (const float*)d_in[3];
    const float* mems    = (const float*)d_in[4];
    const float* gamma_q = (const float*)d_in[5];
    const float* beta_q  = (const float*)d_in[6];
    const float* gamma_kv= (const float*)d_in[7];
    const float* beta_kv = (const float*)d_in[8];
    const float* Wq      = (const float*)d_in[9];
    const float* Wiq     = (const float*)d_in[10];
    const float* Wk      = (const float*)d_in[11];
    const float* Wv      = (const float*)d_in[12];
    const float* Wr      = (const float*)d_in[13];
    const float* Wintra  = (const float*)d_in[14];
    const float* Winter  = (const float*)d_in[15];
    float* out = (float*)d_out;
    float* ws = (float*)d_ws;

    float* corr = ws;                          // 16,384 f32

    ushort* w_norm_bf  = (ushort*)(corr + 16384);
    ushort* kv_norm_bf = w_norm_bf + 2097152;
    ushort* head_q_bf  = kv_norm_bf + 4194304;   // includes r_w_bias
    ushort* head_k_bf  = head_q_bf + 2097152;
    ushort* head_v_bf  = head_k_bf + 4194304;    // contiguous after head_k
    ushort* head_vT_bf = head_v_bf + 4194304;
    ushort* r_hk_bf    = head_vT_bf + 4194304;
    ushort* attn_o_bf  = r_hk_bf + 1048576;
    ushort* r_bf       = attn_o_bf + 2097152;
    ushort* Wk_bf      = r_bf + 1048576;
    ushort* Wv_bf      = Wk_bf + 1048576;        // contiguous after Wk
    ushort* Wr_bf      = Wv_bf + 1048576;
    ushort* Wq_aug     = Wr_bf + 262144;         // [4][256][1024]
    ushort* Wo_aug     = Wq_aug + 1048576;       // [4][256][1024]

    // Partial buffers reuse DEAD regions (all dead before attn runs):
    float* Op0 = (float*)kv_norm_bf;             // dead after head_kv gemm (8MB)
    float* Op1 = (float*)head_v_bf;              // dead after transpose_v (8MB)
    float* Ml  = (float*)w_norm_bf;              // dead after head_q gemm (512KB used)

    group_ln_kernel<<<dim3(Q_LEN * BSZ * NG), 64, 0, stream>>>(w, gamma_q, beta_q, w_norm_bf);
    kv_ln_kernel<<<dim3(KL * BSZ), 256, 0, stream>>>(mems, w, gamma_kv, beta_kv, kv_norm_bf);

    cast4_kernel<<<dim3(3328), 256, 0, stream>>>(
        r, Wk, Wv, Wr, r_bf, Wk_bf, Wv_bf, Wr_bf);
    augment_kernel<<<dim3(2048), 256, 0, stream>>>(
        Wq, Wiq, Wq_aug, Wintra, Winter, Wo_aug);

    // head_k & head_v in ONE 128-tile dispatch (z over {Wk,Wv})
    gemm128_bf16_nt<<<dim3(8, 32, 2), 256, 0, stream>>>(
        kv_norm_bf, DM, Wk_bf, 1048576, DM, head_k_bf, 4194304, DM, DM);
    transpose_v_kernel<<<dim3(16, 64), 256, 0, stream>>>(head_v_bf, head_vT_bf);

    // head_q = w_norm x Wq_aug^T (+rwb), z = group, K = 1024
    gemm_bf16_nt<<<dim3(4, 32, 4), 256, 0, stream>>>(
        w_norm_bf, 0, DM, Wq_aug, 262144, DM, nullptr, head_q_bf, DGRP, DM,
        Q_LEN * BSZ, DGRP, DM, nullptr, 0, 0, rwb, DGRP, 0);
    // r_head_k -> bf16 (grouped, K = 256)
    gemm_bf16_nt<<<dim3(4, 16, 4), 256, 0, stream>>>(
        r_bf, DGRP, DM, Wr_bf, DGRP * DGRP, DGRP, nullptr, r_hk_bf, DGRP, DM,
        RL, DGRP, DGRP, nullptr, 0, 0, nullptr, 0, 0);

    corr_kernel<<<dim3(RL / 4, NH), 256, 0, stream>>>(r_hk_bf, rwb, rrb, corr);

    attn_split_kernel<<<dim3(64, 64), 64, 0, stream>>>(
        head_q_bf, head_k_bf, head_vT_bf, r_hk_bf, corr, Op0, Op1, Ml);
    merge_kernel<<<dim3(2048), 256, 0, stream>>>(Op0, Op1, Ml, attn_o_bf);

    // out = attn_o x Wo_aug^T + w (residual), z = group, K = 1024
    gemm_bf16_nt<<<dim3(4, 32, 4), 256, 0, stream>>>(
        attn_o_bf, 0, DM, Wo_aug, 262144, DM, out, nullptr, DGRP, DM,
        Q_LEN * BSZ, DGRP, DM, w, DGRP, DM, nullptr, 0, 0);
}

// Round 15
// 161.770 us; speedup vs baseline: 1.2060x; 1.2060x over previous
//
#include <hip/hip_runtime.h>
#include <math.h>

#define Q_LEN 512
#define M_LEN 512
#define KL    1024
#define BSZ   4
#define DM    1024
#define NH    16
#define DHD   64
#define NG    4
#define DGRP  256
#define RL    1024
#define LN_EPS 1e-6f
#define ATT_SCALE 0.125f

typedef short s16x8 __attribute__((ext_vector_type(8)));
typedef float f32x4 __attribute__((ext_vector_type(4)));

__device__ __forceinline__ float wave_sum64(float v) {
#pragma unroll
    for (int off = 32; off > 0; off >>= 1) v += __shfl_xor(v, off);
    return v;
}

__device__ __forceinline__ ushort f2bf(float f) {
    unsigned u = __float_as_uint(f);
    unsigned r = (u + 0x7fffu + ((u >> 16) & 1u)) >> 16;   // RNE
    return (ushort)r;
}
__device__ __forceinline__ float bf2f(ushort u) {
    return __uint_as_float(((unsigned)u) << 16);
}

// ------- fused prep: cast {r,Wk,Wv,Wr} + build augmented {Wq_aug,Wo_aug} ----
// W'[g][o][k] = Wfull[o][k] + (k>>8==g ? Wg[g][o][k&255] : 0)
__global__ __launch_bounds__(256) void prep_kernel(
    const float* __restrict__ r, const float* __restrict__ Wk,
    const float* __restrict__ Wv, const float* __restrict__ Wr,
    const float* __restrict__ Wq, const float* __restrict__ Wiq,
    const float* __restrict__ Wintra, const float* __restrict__ Winter,
    ushort* __restrict__ r_bf, ushort* __restrict__ Wk_bf,
    ushort* __restrict__ Wv_bf, ushort* __restrict__ Wr_bf,
    ushort* __restrict__ Wq_aug, ushort* __restrict__ Wo_aug)
{
    int bid = blockIdx.x;
    if (bid < 3328) {
        const float* s; ushort* d; int off;
        if      (bid < 1024) { s = r;  d = r_bf;  off = bid; }
        else if (bid < 2048) { s = Wk; d = Wk_bf; off = bid - 1024; }
        else if (bid < 3072) { s = Wv; d = Wv_bf; off = bid - 2048; }
        else                 { s = Wr; d = Wr_bf; off = bid - 3072; }
        int i = off * 1024 + threadIdx.x * 4;
        float4 v = *(const float4*)(s + i);
        ushort4 o;
        o.x = f2bf(v.x); o.y = f2bf(v.y); o.z = f2bf(v.z); o.w = f2bf(v.w);
        *(ushort4*)(d + i) = o;
    } else {
        const float* Wg; const float* Wf; ushort* Wo; int off;
        if (bid < 4352) { Wg = Wq;     Wf = Wiq;    Wo = Wq_aug; off = bid - 3328; }
        else            { Wg = Wintra; Wf = Winter; Wo = Wo_aug; off = bid - 4352; }
        int idx = off * 1024 + threadIdx.x * 4;      // over 4*256*1024
        int g = idx >> 18;
        int o = (idx >> 10) & 255;
        int k = idx & 1023;
        float4 v = *(const float4*)(Wf + o * 1024 + k);
        if ((k >> 8) == g) {
            float4 vg = *(const float4*)(Wg + ((g * 256 + o) << 8) + (k & 255));
            v.x += vg.x; v.y += vg.y; v.z += vg.z; v.w += vg.w;
        }
        ushort4 u;
        u.x = f2bf(v.x); u.y = f2bf(v.y); u.z = f2bf(v.z); u.w = f2bf(v.w);
        *(ushort4*)(Wo + idx) = u;
    }
}

// ---------------- group LayerNorm for w (G=4 groups of 256) -> bf16 --------
__global__ __launch_bounds__(64) void group_ln_kernel(
    const float* __restrict__ w, const float* __restrict__ gamma,
    const float* __restrict__ beta, ushort* __restrict__ out)
{
    int bid = blockIdx.x;              // (q*BSZ + b)*NG + g
    int g = bid & (NG - 1);
    long long row = bid >> 2;
    int t = threadIdx.x;
    long long base = row * DM + g * DGRP + t * 4;
    float4 x = *(const float4*)(w + base);
    float mean = wave_sum64(x.x + x.y + x.z + x.w) * (1.0f / 256.0f);
    float dx = x.x - mean, dy = x.y - mean, dz = x.z - mean, dw = x.w - mean;
    float ss = wave_sum64(dx * dx + dy * dy + dz * dz + dw * dw);
    float inv = 1.0f / (sqrtf(ss * (1.0f / 255.0f)) + LN_EPS);   // ddof=1
    int db = g * DGRP + t * 4;
    float4 ga = *(const float4*)(gamma + db);
    float4 be = *(const float4*)(beta + db);
    ushort4 o;
    o.x = f2bf(ga.x * (dx * inv) + be.x);
    o.y = f2bf(ga.y * (dy * inv) + be.y);
    o.z = f2bf(ga.z * (dz * inv) + be.z);
    o.w = f2bf(ga.w * (dw * inv) + be.w);
    *(ushort4*)(out + base) = o;
}

// ---------------- full LayerNorm for kv = concat(mems, w) -> bf16 ----------
__global__ __launch_bounds__(256) void kv_ln_kernel(
    const float* __restrict__ mems, const float* __restrict__ w,
    const float* __restrict__ gamma, const float* __restrict__ beta,
    ushort* __restrict__ out)
{
    int row = blockIdx.x;              // k*BSZ + b
    int k = row >> 2, b = row & 3;
    const float* src = (k < M_LEN) ? (mems + ((long long)k * BSZ + b) * DM)
                                   : (w + ((long long)(k - M_LEN) * BSZ + b) * DM);
    int t = threadIdx.x;
    float4 x = *(const float4*)(src + t * 4);
    __shared__ float red[4];
    float s = wave_sum64(x.x + x.y + x.z + x.w);
    int wv = t >> 6, ln = t & 63;
    if (ln == 0) red[wv] = s;
    __syncthreads();
    float mean = (red[0] + red[1] + red[2] + red[3]) * (1.0f / 1024.0f);
    float dx = x.x - mean, dy = x.y - mean, dz = x.z - mean, dw = x.w - mean;
    float ss = wave_sum64(dx * dx + dy * dy + dz * dz + dw * dw);
    __syncthreads();
    if (ln == 0) red[wv] = ss;
    __syncthreads();
    float var = (red[0] + red[1] + red[2] + red[3]) * (1.0f / 1023.0f);
    float inv = 1.0f / (sqrtf(var) + LN_EPS);
    int db = t * 4;
    float4 ga = *(const float4*)(gamma + db);
    float4 be = *(const float4*)(beta + db);
    ushort4 o;
    o.x = f2bf(ga.x * (dx * inv) + be.x);
    o.y = f2bf(ga.y * (dy * inv) + be.y);
    o.z = f2bf(ga.z * (dz * inv) + be.z);
    o.w = f2bf(ga.w * (dw * inv) + be.w);
    *(ushort4*)(out + (long long)row * DM + db) = o;
}

// ------ 128x128-tile bf16 MFMA GEMM  Cb = A[M,K] * W[N,K]^T (bf16 out) -----
__global__ __launch_bounds__(256) void gemm128_bf16_nt(
    const ushort* __restrict__ A, int lda,
    const ushort* __restrict__ W, long long wZ, int ldw,
    ushort* __restrict__ Cb, long long cZ, int ldc, int K)
{
    int z = blockIdx.z;
    W += (long long)z * wZ;
    Cb += (long long)z * cZ;
    int m0 = blockIdx.y * 128, n0 = blockIdx.x * 128;
    int t = threadIdx.x, lane = t & 63, w = t >> 6;
    int wr = w >> 1, wc = w & 1;
    int fr = lane & 15, kq = (lane >> 4) * 8;
    int srow = t >> 1, scol = (t & 1) * 16;

    __shared__ __align__(16) ushort As[128][40];
    __shared__ __align__(16) ushort Ws[128][40];

    const ushort* Ar = A + (long long)(m0 + srow) * lda + scol;
    const ushort* Wr = W + (long long)(n0 + srow) * ldw + scol;

    f32x4 acc[16] = {};

    s16x8 a0 = *(const s16x8*)Ar, a1 = *(const s16x8*)(Ar + 8);
    s16x8 b0 = *(const s16x8*)Wr, b1 = *(const s16x8*)(Wr + 8);
    *(s16x8*)&As[srow][scol] = a0; *(s16x8*)&As[srow][scol + 8] = a1;
    *(s16x8*)&Ws[srow][scol] = b0; *(s16x8*)&Ws[srow][scol + 8] = b1;
    __syncthreads();

    for (int k0 = 0; k0 < K; k0 += 32) {
        bool more = (k0 + 32) < K;
        if (more) {
            a0 = *(const s16x8*)(Ar + k0 + 32); a1 = *(const s16x8*)(Ar + k0 + 40);
            b0 = *(const s16x8*)(Wr + k0 + 32); b1 = *(const s16x8*)(Wr + k0 + 40);
        }
        s16x8 af[4], bf_[4];
#pragma unroll
        for (int rb = 0; rb < 4; ++rb)
            af[rb] = *(const s16x8*)&As[wr * 64 + rb * 16 + fr][kq];
#pragma unroll
        for (int cb = 0; cb < 4; ++cb)
            bf_[cb] = *(const s16x8*)&Ws[wc * 64 + cb * 16 + fr][kq];
#pragma unroll
        for (int rb = 0; rb < 4; ++rb)
#pragma unroll
            for (int cb = 0; cb < 4; ++cb)
                acc[rb * 4 + cb] = __builtin_amdgcn_mfma_f32_16x16x32_bf16(
                    af[rb], bf_[cb], acc[rb * 4 + cb], 0, 0, 0);
        __syncthreads();
        if (more) {
            *(s16x8*)&As[srow][scol] = a0; *(s16x8*)&As[srow][scol + 8] = a1;
            *(s16x8*)&Ws[srow][scol] = b0; *(s16x8*)&Ws[srow][scol + 8] = b1;
            __syncthreads();
        }
    }

    int rbase = (lane >> 4) * 4;
#pragma unroll
    for (int rb = 0; rb < 4; ++rb)
#pragma unroll
        for (int p = 0; p < 4; ++p) {
            long long row = m0 + wr * 64 + rb * 16 + rbase + p;
            ushort* crow = Cb + row * ldc + n0 + wc * 64 + fr;
#pragma unroll
            for (int cb = 0; cb < 4; ++cb)
                crow[cb * 16] = f2bf(acc[rb * 4 + cb][p]);
        }
}

// ------ 64x64-tile bf16 MFMA GEMM (BK=64 + reg prefetch), f32/bf16 out -----
__global__ __launch_bounds__(256) void gemm_bf16_nt(
    const ushort* __restrict__ A, long long aZ, int lda,
    const ushort* __restrict__ W, long long wZ, int ldw,
    float* __restrict__ C, ushort* __restrict__ Cb, long long cZ, int ldc,
    int M, int N, int K,
    const float* __restrict__ add1, long long a1Z, int lda1,
    const float* __restrict__ add2, long long a2Z, int lda2)
{
    int z = blockIdx.z;
    A += (long long)z * aZ;
    W += (long long)z * wZ;
    if (C)  C += (long long)z * cZ;
    if (Cb) Cb += (long long)z * cZ;
    if (add1) add1 += (long long)z * a1Z;
    if (add2) add2 += (long long)z * a2Z;
    int m0 = blockIdx.y * 64, n0 = blockIdx.x * 64;
    int t = threadIdx.x;
    int lane = t & 63, wid = t >> 6;
    int wr = wid >> 1, wc = wid & 1;
    int srow = t >> 2, scol = (t & 3) * 16;
    int fr = lane & 15, kq = (lane >> 4) * 8;

    __shared__ __align__(16) ushort As[64][72];
    __shared__ __align__(16) ushort Ws[64][72];

    f32x4 acc00 = {}, acc01 = {}, acc10 = {}, acc11 = {};

    const ushort* Arow = A + (long long)(m0 + srow) * lda + scol;
    const ushort* Wrow = W + (long long)(n0 + srow) * ldw + scol;

    s16x8 ra0 = *(const s16x8*)Arow;
    s16x8 ra1 = *(const s16x8*)(Arow + 8);
    s16x8 rw0 = *(const s16x8*)Wrow;
    s16x8 rw1 = *(const s16x8*)(Wrow + 8);
    *(s16x8*)&As[srow][scol] = ra0; *(s16x8*)&As[srow][scol + 8] = ra1;
    *(s16x8*)&Ws[srow][scol] = rw0; *(s16x8*)&Ws[srow][scol + 8] = rw1;
    __syncthreads();

    for (int k0 = 0; k0 < K; k0 += 64) {
        bool hasNext = (k0 + 64) < K;
        if (hasNext) {
            ra0 = *(const s16x8*)(Arow + k0 + 64);
            ra1 = *(const s16x8*)(Arow + k0 + 72);
            rw0 = *(const s16x8*)(Wrow + k0 + 64);
            rw1 = *(const s16x8*)(Wrow + k0 + 72);
        }
#pragma unroll
        for (int kk = 0; kk < 64; kk += 32) {
            s16x8 a0 = *(const s16x8*)&As[wr * 32 + fr][kk + kq];
            s16x8 a1 = *(const s16x8*)&As[wr * 32 + 16 + fr][kk + kq];
            s16x8 b0 = *(const s16x8*)&Ws[wc * 32 + fr][kk + kq];
            s16x8 b1 = *(const s16x8*)&Ws[wc * 32 + 16 + fr][kk + kq];
            acc00 = __builtin_amdgcn_mfma_f32_16x16x32_bf16(a0, b0, acc00, 0, 0, 0);
            acc01 = __builtin_amdgcn_mfma_f32_16x16x32_bf16(a0, b1, acc01, 0, 0, 0);
            acc10 = __builtin_amdgcn_mfma_f32_16x16x32_bf16(a1, b0, acc10, 0, 0, 0);
            acc11 = __builtin_amdgcn_mfma_f32_16x16x32_bf16(a1, b1, acc11, 0, 0, 0);
        }
        __syncthreads();
        if (hasNext) {
            *(s16x8*)&As[srow][scol] = ra0; *(s16x8*)&As[srow][scol + 8] = ra1;
            *(s16x8*)&Ws[srow][scol] = rw0; *(s16x8*)&Ws[srow][scol + 8] = rw1;
            __syncthreads();
        }
    }

    int rbase = (lane >> 4) * 4;
#pragma unroll
    for (int p = 0; p < 4; ++p) {
        int mrow0 = wr * 32 + rbase + p;
        int mrow1 = mrow0 + 16;
        int ncol0 = wc * 32 + fr;
        int ncol1 = ncol0 + 16;
        float v00 = acc00[p], v01 = acc01[p], v10 = acc10[p], v11 = acc11[p];
        long long r0 = m0 + mrow0, r1 = m0 + mrow1;
        int c0 = n0 + ncol0, c1 = n0 + ncol1;
        if (add1) {
            v00 += add1[r0 * lda1 + c0]; v01 += add1[r0 * lda1 + c1];
            v10 += add1[r1 * lda1 + c0]; v11 += add1[r1 * lda1 + c1];
        }
        if (add2) {
            v00 += add2[r0 * lda2 + c0]; v01 += add2[r0 * lda2 + c1];
            v10 += add2[r1 * lda2 + c0]; v11 += add2[r1 * lda2 + c1];
        }
        if (Cb) {
            Cb[r0 * ldc + c0] = f2bf(v00); Cb[r0 * ldc + c1] = f2bf(v01);
            Cb[r1 * ldc + c0] = f2bf(v10); Cb[r1 * ldc + c1] = f2bf(v11);
        } else {
            C[r0 * ldc + c0] = v00; C[r0 * ldc + c1] = v01;
            C[r1 * ldc + c0] = v10; C[r1 * ldc + c1] = v11;
        }
    }
}

// --------- transpose head_v: [k*4+b][n*64+d] -> [(b*16+n)*64+d][k] ---------
__global__ __launch_bounds__(256) void transpose_v_kernel(
    const ushort* __restrict__ vin, ushort* __restrict__ vout)
{
    __shared__ __align__(16) ushort T[64][72];
    int bn = blockIdx.y;
    int b = bn >> 4, n = bn & 15;
    int k0 = blockIdx.x * 64;
    int t = threadIdx.x;
    {
        int kr = t >> 2, dp = (t & 3) * 16;
        const ushort* sp = vin + (((long long)(k0 + kr)) * 4 + b) * DM + n * DHD + dp;
        *(s16x8*)&T[kr][dp] = *(const s16x8*)sp;
        *(s16x8*)&T[kr][dp + 8] = *(const s16x8*)(sp + 8);
    }
    __syncthreads();
    {
        int d = t >> 2, kp = (t & 3) * 16;
        ushort vals[16];
#pragma unroll
        for (int q = 0; q < 16; ++q) vals[q] = T[kp + q][d];
        ushort* dp = vout + ((long long)bn * DHD + d) * KL + k0 + kp;
        *(s16x8*)dp = *(const s16x8*)&vals[0];
        *(s16x8*)(dp + 8) = *(const s16x8*)&vals[8];
    }
}

// --------- corr[n,k] = sum_d (rrb[n,d]-rwb[n,d]) * r_head_k[k,n,d] ---------
__global__ __launch_bounds__(256) void corr_kernel(
    const ushort* __restrict__ r_hk, const float* __restrict__ rwb,
    const float* __restrict__ rrb, float* __restrict__ corr)
{
    int n = blockIdx.y;
    int k = blockIdx.x * 4 + (threadIdx.x >> 6);
    int d = threadIdx.x & 63;
    float diff = rrb[n * DHD + d] - rwb[n * DHD + d];
    float v = diff * bf2f(r_hk[(long long)k * DM + n * DHD + d]);
    v = wave_sum64(v);
    if (d == 0) corr[n * RL + k] = v;
}

// ---------------- MFMA flash rel-shift attention (R11-verified + setprio) --
// grid (8, 64); 4 waves; wave w owns q-rows [w*16, w*16+16).
// K/V double-buffered; RKs 128-row ring; BDs/Ps wave-private (no barrier);
// ONE __syncthreads() per tile (tile 0: two).
__global__ __launch_bounds__(256) void attn_mfma_kernel(
    const ushort* __restrict__ hq, const ushort* __restrict__ hk,
    const ushort* __restrict__ hvT, const ushort* __restrict__ rhk,
    const float* __restrict__ corr, ushort* __restrict__ attn_out)
{
    __shared__ __align__(16) ushort Ks[2][64][72];
    __shared__ __align__(16) ushort VsT[2][64][72];
    __shared__ __align__(16) ushort RKs[128][72];
    __shared__ __align__(16) ushort BDs[64][128];
    __shared__ __align__(16) ushort Ps[64][64];

    int bh = blockIdx.y;
    int b = bh >> 4, n = bh & 15;
    int i0 = blockIdx.x * 64;
    int t = threadIdx.x;
    int lane = t & 63, w = t >> 6;
    int lr16 = lane & 15;
    int lk8 = (lane >> 4) * 8;
    int orow = (lane >> 4) * 4;
    int swzBD = ((lane >> 4) & 3) << 4;

    s16x8 qf0, qf1;
    {
        const ushort* qp = hq + (((long long)(i0 + w * 16 + lr16)) * 4 + b) * DM
                              + n * DHD + lk8;
        qf0 = *(const s16x8*)qp;
        qf1 = *(const s16x8*)(qp + 32);
    }

    f32x4 O[4] = {};
    float m_[4], l_[4];
#pragma unroll
    for (int r = 0; r < 4; ++r) { m_[r] = -INFINITY; l_[r] = 0.0f; }

    int nJ = ((i0 + 575) >> 6) + 1;
    if (nJ > 16) nJ = 16;
    int ka0 = 448 - i0;

    int srow = t >> 2, sdp = (t & 3) * 16;

    {
        const ushort* kp = hk + (((long long)srow) * 4 + b) * DM + n * DHD + sdp;
        *(s16x8*)&Ks[0][srow][sdp] = *(const s16x8*)kp;
        *(s16x8*)&Ks[0][srow][sdp + 8] = *(const s16x8*)(kp + 8);
        const ushort* vp = hvT + ((long long)bh * DHD + srow) * KL + sdp;
        *(s16x8*)&VsT[0][srow][sdp] = *(const s16x8*)vp;
        *(s16x8*)&VsT[0][srow][sdp + 8] = *(const s16x8*)(vp + 8);
        int rr = t >> 1, dp2 = (t & 1) * 32;
        int rabs = ka0 + rr;
        const ushort* rp = rhk + (long long)rabs * DM + n * DHD + dp2;
        int phys = rabs & 127;
#pragma unroll
        for (int q = 0; q < 4; ++q)
            *(s16x8*)&RKs[phys][dp2 + q * 8] = *(const s16x8*)(rp + q * 8);
    }
    __syncthreads();

    int cur = 0;
    for (int jt = 0; jt < nJ; ++jt) {
        int j0 = jt * 64;
        int ka = ka0 + j0;
        bool hasNext = (jt + 1) < nJ;

        s16x8 pk0 = {}, pk1 = {}, pv0 = {}, pv1 = {}, pr0 = {}, pr1 = {};
        if (hasNext) {
            int j0n = j0 + 64;
            const ushort* kp = hk + (((long long)(j0n + srow)) * 4 + b) * DM + n * DHD + sdp;
            pk0 = *(const s16x8*)kp;
            pk1 = *(const s16x8*)(kp + 8);
            const ushort* vp = hvT + ((long long)bh * DHD + srow) * KL + j0n + sdp;
            pv0 = *(const s16x8*)vp;
            pv1 = *(const s16x8*)(vp + 8);
            int rnew = ka + 128 + srow;
            if (rnew < RL) {
                const ushort* rp = rhk + (long long)rnew * DM + n * DHD + sdp;
                pr0 = *(const s16x8*)rp;
                pr1 = *(const s16x8*)(rp + 8);
            }
        }

        __builtin_amdgcn_s_setprio(1);
        f32x4 ac[4] = {};
#pragma unroll
        for (int nb = 0; nb < 4; ++nb) {
            s16x8 kb0 = *(const s16x8*)&Ks[cur][nb * 16 + lr16][lk8];
            s16x8 kb1 = *(const s16x8*)&Ks[cur][nb * 16 + lr16][32 + lk8];
            ac[nb] = __builtin_amdgcn_mfma_f32_16x16x32_bf16(qf0, kb0, ac[nb], 0, 0, 0);
            ac[nb] = __builtin_amdgcn_mfma_f32_16x16x32_bf16(qf1, kb1, ac[nb], 0, 0, 0);
        }
        int nb0 = (jt == 0) ? 0 : 4;
        for (int nb = nb0; nb < 8; ++nb) {
            int kk = nb * 16 + lr16;
            int rabs = ka + kk;
            int phys = rabs & 127;
            f32x4 bd = {};
            s16x8 rb0 = *(const s16x8*)&RKs[phys][lk8];
            s16x8 rb1 = *(const s16x8*)&RKs[phys][32 + lk8];
            bd = __builtin_amdgcn_mfma_f32_16x16x32_bf16(qf0, rb0, bd, 0, 0, 0);
            bd = __builtin_amdgcn_mfma_f32_16x16x32_bf16(qf1, rb1, bd, 0, 0, 0);
            float cadd = (rabs < RL) ? corr[n * RL + rabs] : 0.0f;
            int colw = phys ^ swzBD;
#pragma unroll
            for (int reg = 0; reg < 4; ++reg)
                BDs[w * 16 + orow + reg][colw] = f2bf(bd[reg] + cadd);
        }
        __builtin_amdgcn_s_setprio(0);
        if (jt == 0) __syncthreads();

        float pvv[4][4], rowm[4];
#pragma unroll
        for (int reg = 0; reg < 4; ++reg) {
            int il = w * 16 + orow + reg;
            int i = i0 + il;
            rowm[reg] = -INFINITY;
#pragma unroll
            for (int nb = 0; nb < 4; ++nb) {
                int jc = nb * 16 + lr16;
                int j = j0 + jc;
                float s = -INFINITY;
                if (j <= i + M_LEN) {
                    int phys = (j + 511 - i) & 127;
                    s = (ac[nb][reg] + bf2f(BDs[il][phys ^ swzBD])) * ATT_SCALE;
                }
                pvv[reg][nb] = s;
                rowm[reg] = fmaxf(rowm[reg], s);
            }
        }
#pragma unroll
        for (int st = 1; st <= 8; st <<= 1)
#pragma unroll
            for (int reg = 0; reg < 4; ++reg)
                rowm[reg] = fmaxf(rowm[reg], __shfl_xor(rowm[reg], st));
        float rs[4], alpha[4];
#pragma unroll
        for (int reg = 0; reg < 4; ++reg) {
            int il = w * 16 + orow + reg;
            float newm = fmaxf(m_[reg], rowm[reg]);
            alpha[reg] = __expf(m_[reg] - newm);
            m_[reg] = newm;
            rs[reg] = 0.0f;
#pragma unroll
            for (int nb = 0; nb < 4; ++nb) {
                float p = __expf(pvv[reg][nb] - newm);
                rs[reg] += p;
                int jc = nb * 16 + lr16;
                int colp = (((jc >> 3) ^ (il & 7)) << 3) | (jc & 7);
                Ps[il][colp] = f2bf(p);
            }
        }
#pragma unroll
        for (int st = 1; st <= 8; st <<= 1)
#pragma unroll
            for (int reg = 0; reg < 4; ++reg)
                rs[reg] += __shfl_xor(rs[reg], st);
#pragma unroll
        for (int reg = 0; reg < 4; ++reg) {
            l_[reg] = l_[reg] * alpha[reg] + rs[reg];
#pragma unroll
            for (int nb = 0; nb < 4; ++nb) O[nb][reg] *= alpha[reg];
        }

        {
            int prow = w * 16 + lr16;
            int rh = prow & 7;
            __builtin_amdgcn_s_setprio(1);
#pragma unroll
            for (int kc = 0; kc < 2; ++kc) {
                int blk = kc * 4 + (lane >> 4);
                s16x8 pa = *(const s16x8*)&Ps[prow][(blk ^ rh) << 3];
#pragma unroll
                for (int nb = 0; nb < 4; ++nb) {
                    s16x8 vb = *(const s16x8*)&VsT[cur][nb * 16 + lr16][kc * 32 + lk8];
                    O[nb] = __builtin_amdgcn_mfma_f32_16x16x32_bf16(pa, vb, O[nb], 0, 0, 0);
                }
            }
            __builtin_amdgcn_s_setprio(0);
        }

        if (hasNext) {
            *(s16x8*)&Ks[cur ^ 1][srow][sdp] = pk0;
            *(s16x8*)&Ks[cur ^ 1][srow][sdp + 8] = pk1;
            *(s16x8*)&VsT[cur ^ 1][srow][sdp] = pv0;
            *(s16x8*)&VsT[cur ^ 1][srow][sdp + 8] = pv1;
            int phys = (ka + 128 + srow) & 127;
            *(s16x8*)&RKs[phys][sdp] = pr0;
            *(s16x8*)&RKs[phys][sdp + 8] = pr1;
        }
        __syncthreads();
        cur ^= 1;
    }

#pragma unroll
    for (int reg = 0; reg < 4; ++reg) {
        int il = w * 16 + orow + reg;
        long long i = i0 + il;
        float inv = 1.0f / l_[reg];
#pragma unroll
        for (int nb = 0; nb < 4; ++nb)
            attn_out[(i * 4 + b) * DM + n * DHD + nb * 16 + lr16] = f2bf(O[nb][reg] * inv);
    }
}

extern "C" void kernel_launch(void* const* d_in, const int* in_sizes, int n_in,
                              void* d_out, int out_size, void* d_ws, size_t ws_size,
                              hipStream_t stream) {
    const float* w       = (const float*)d_in[0];
    const float* r       = (const float*)d_in[1];
    const float* rwb     = (const float*)d_in[2];
    const float* rrb     = (const float*)d_in[3];
    const float* mems    = (const float*)d_in[4];
    const float* gamma_q = (const float*)d_in[5];
    const float* beta_q  = (const float*)d_in[6];
    const float* gamma_kv= (const float*)d_in[7];
    const float* beta_kv = (const float*)d_in[8];
    const float* Wq      = (const float*)d_in[9];
    const float* Wiq     = (const float*)d_in[10];
    const float* Wk      = (const float*)d_in[11];
    const float* Wv      = (const float*)d_in[12];
    const float* Wr      = (const float*)d_in[13];
    const float* Wintra  = (const float*)d_in[14];
    const float* Winter  = (const float*)d_in[15];
    float* out = (float*)d_out;
    float* ws = (float*)d_ws;

    float* corr = ws;                          // 16,384 f32

    ushort* w_norm_bf  = (ushort*)(corr + 16384);
    ushort* kv_norm_bf = w_norm_bf + 2097152;
    ushort* head_q_bf  = kv_norm_bf + 4194304;   // includes r_w_bias
    ushort* head_k_bf  = head_q_bf + 2097152;
    ushort* head_v_bf  = head_k_bf + 4194304;    // contiguous after head_k
    ushort* head_vT_bf = head_v_bf + 4194304;
    ushort* r_hk_bf    = head_vT_bf + 4194304;
    ushort* attn_o_bf  = r_hk_bf + 1048576;
    ushort* r_bf       = attn_o_bf + 2097152;
    ushort* Wk_bf      = r_bf + 1048576;
    ushort* Wv_bf      = Wk_bf + 1048576;        // contiguous after Wk
    ushort* Wr_bf      = Wv_bf + 1048576;
    ushort* Wq_aug     = Wr_bf + 262144;         // [4][256][1024]
    ushort* Wo_aug     = Wq_aug + 1048576;       // [4][256][1024]

    group_ln_kernel<<<dim3(Q_LEN * BSZ * NG), 64, 0, stream>>>(w, gamma_q, beta_q, w_norm_bf);
    kv_ln_kernel<<<dim3(KL * BSZ), 256, 0, stream>>>(mems, w, gamma_kv, beta_kv, kv_norm_bf);

    prep_kernel<<<dim3(5376), 256, 0, stream>>>(
        r, Wk, Wv, Wr, Wq, Wiq, Wintra, Winter,
        r_bf, Wk_bf, Wv_bf, Wr_bf, Wq_aug, Wo_aug);

    // head_k & head_v in ONE 128-tile dispatch (z over {Wk,Wv})
    gemm128_bf16_nt<<<dim3(8, 32, 2), 256, 0, stream>>>(
        kv_norm_bf, DM, Wk_bf, 1048576, DM, head_k_bf, 4194304, DM, DM);
    transpose_v_kernel<<<dim3(16, 64), 256, 0, stream>>>(head_v_bf, head_vT_bf);

    // head_q = w_norm x Wq_aug^T (+rwb), z = group, K = 1024
    gemm_bf16_nt<<<dim3(4, 32, 4), 256, 0, stream>>>(
        w_norm_bf, 0, DM, Wq_aug, 262144, DM, nullptr, head_q_bf, DGRP, DM,
        Q_LEN * BSZ, DGRP, DM, nullptr, 0, 0, rwb, DGRP, 0);
    // r_head_k -> bf16 (grouped, K = 256)
    gemm_bf16_nt<<<dim3(4, 16, 4), 256, 0, stream>>>(
        r_bf, DGRP, DM, Wr_bf, DGRP * DGRP, DGRP, nullptr, r_hk_bf, DGRP, DM,
        RL, DGRP, DGRP, nullptr, 0, 0, nullptr, 0, 0);

    corr_kernel<<<dim3(RL / 4, NH), 256, 0, stream>>>(r_hk_bf, rwb, rrb, corr);

    attn_mfma_kernel<<<dim3(Q_LEN / 64, BSZ * NH), 256, 0, stream>>>(
        head_q_bf, head_k_bf, head_vT_bf, r_hk_bf, corr, attn_o_bf);

    // out = attn_o x Wo_aug^T + w (residual), z = group, K = 1024
    gemm_bf16_nt<<<dim3(4, 32, 4), 256, 0, stream>>>(
        attn_o_bf, 0, DM, Wo_aug, 262144, DM, out, nullptr, DGRP, DM,
        Q_LEN * BSZ, DGRP, DM, w, DGRP, DM, nullptr, 0, 0);
}